// Round 14
// baseline (137.701 us; speedup 1.0000x reference)
//
#include <hip/hip_runtime.h>

// SidedDistance: for each point in S1 (B,N,3), index (base-1) of nearest point
// in S2 (B,M,3). B=4, N=M=8192. Output int32. PASSING MODEL (R9-R11, absmax=32):
//   d2 bits = fwd-nonFMA expansion:  n = (x*x + y*y) + z*z ;
//   cross = (ax*bx + ay*by) + az*bz ; d2 = fma(cross,-2,n1) + n2
//   (fma form bit-equal to (n1-2c)+n2 since 2c is exact; verified R11 pass)
//   tie policy: first & last index of the min; emit LAST if gap>=3000 else
//   FIRST; output idx+1.  DO NOT touch numerics/tie policy.
//
// R11 post-mortem: ext_vector packing made loop-variant {p.x,p.x} splats ->
// per-candidate movs; 16-wave single-block barriers serialized the CU.
// R12: (1) pack CANDIDATE pairs in LDS (SoA pairs -> ds_read_b128 feeds
// v_pk_*_f32 directly, splats loop-invariant, asm-forced packing);
// (2) 2 independent blocks/CU (70KB LDS, grid 512) so staging overlaps
// compute across blocks. 1 query/lane, contiguous per-wave candidate chunks.
// (R12 and R13 benches were GPUAcquisitionTimeouts — resubmitting identical.)

#define BATCHES 4
#define NQ 8192
#define NM 8192
#define QG 64          // queries per block = 1 per lane
#define NWAVES 8
#define TILE 4096      // candidates per LDS tile (2 tiles)
#define NTILES (NM / TILE)
#define CHUNK (TILE / NWAVES)   // 512 contiguous candidates per wave per tile
#define GAP_LAST_THRESH 3000

typedef float v2f __attribute__((ext_vector_type(2)));

struct Pair { float4 a;   // {x0, x1, y0, y1}
              float4 b; };// {z0, z1, n2_0, n2_1}

__device__ __forceinline__ v2f pk_mul(v2f x, v2f y) {
    v2f d; asm("v_pk_mul_f32 %0, %1, %2" : "=v"(d) : "v"(x), "v"(y)); return d;
}
__device__ __forceinline__ v2f pk_add(v2f x, v2f y) {
    v2f d; asm("v_pk_add_f32 %0, %1, %2" : "=v"(d) : "v"(x), "v"(y)); return d;
}
__device__ __forceinline__ v2f pk_fma(v2f x, v2f y, v2f z) {
    v2f d; asm("v_pk_fma_f32 %0, %1, %2, %3" : "=v"(d) : "v"(x), "v"(y), "v"(z)); return d;
}

__global__ __launch_bounds__(512, 4)
void sided_distance_kernel(const float* __restrict__ S1,
                           const float* __restrict__ S2,
                           int* __restrict__ out) {
#pragma clang fp contract(off)
    __shared__ Pair pairs[TILE / 2];        // 64 KB
    __shared__ float red_d[NWAVES][QG];     // 2 KB
    __shared__ int   red_f[NWAVES][QG];     // 2 KB
    __shared__ int   red_l[NWAVES][QG];     // 2 KB

    const int tid    = threadIdx.x;
    const int lane   = tid & 63;
    const int w      = __builtin_amdgcn_readfirstlane(tid >> 6);
    const int bid    = blockIdx.x;
    const int batch  = bid >> 7;            // 128 blocks per batch
    const int qgroup = bid & 127;
    const int q      = qgroup * QG + lane;

    // n1 exactly as np.sum(S1*S1,-1): (x*x + y*y) + z*z, forward, no FMA.
    const float* a = S1 + ((size_t)batch * NQ + q) * 3;
    const float ax = a[0], ay = a[1], az = a[2];
    const float n1 = __fadd_rn(__fadd_rn(__fmul_rn(ax, ax), __fmul_rn(ay, ay)),
                               __fmul_rn(az, az));

    // Loop-invariant packed query splats.
    const v2f axv = {ax, ax}, ayv = {ay, ay}, azv = {az, az};
    const v2f n1v = {n1, n1};
    const v2f m2v = {-2.0f, -2.0f};

    float bd = 3.4e38f;
    int   fm = 0, lm = 0;

    const float* s2b = S2 + (size_t)batch * NM * 3;

    for (int t = 0; t < NTILES; ++t) {
        __syncthreads();   // protect LDS from previous tile's readers
        const float* g = s2b + (size_t)t * TILE * 3;
        // Stage TILE candidates as SoA pairs; slot s covers cands 2s, 2s+1.
        for (int s = tid; s < TILE / 2; s += 512) {
            const float* c = g + 6 * (size_t)s;
            const float x0 = c[0], y0 = c[1], z0 = c[2];
            const float x1 = c[3], y1 = c[4], z1 = c[5];
            const float n20 = __fadd_rn(__fadd_rn(__fmul_rn(x0, x0), __fmul_rn(y0, y0)),
                                        __fmul_rn(z0, z0));
            const float n21 = __fadd_rn(__fadd_rn(__fmul_rn(x1, x1), __fmul_rn(y1, y1)),
                                        __fmul_rn(z1, z1));
            pairs[s].a = make_float4(x0, x1, y0, y1);
            pairs[s].b = make_float4(z0, z1, n20, n21);
        }
        __syncthreads();

        // Wave w scans contiguous candidates [w*CHUNK, (w+1)*CHUNK), 2/iter.
        const Pair* wp = pairs + w * (CHUNK / 2);
        const int mbase = t * TILE + w * CHUNK;
        #pragma unroll 4
        for (int j = 0; j < CHUNK / 2; ++j) {
            const float4 A = wp[j].a;       // broadcast ds_read_b128
            const float4 B = wp[j].b;
            const v2f x01  = {A.x, A.y};
            const v2f y01  = {A.z, A.w};
            const v2f z01  = {B.x, B.y};
            const v2f n201 = {B.z, B.w};
            // Packed fwd-nonFMA expansion (per-half IEEE == scalar chain):
            const v2f cv  = pk_add(pk_add(pk_mul(axv, x01), pk_mul(ayv, y01)),
                                   pk_mul(azv, z01));
            const v2f d2v = pk_add(pk_fma(cv, m2v, n1v), n201);
            const int m0 = mbase + 2 * j;
            // Bookkeeping: candidate m0 then m0+1 (ascending scan order).
            {
                const float d2 = d2v.x;
                const bool lt = d2 < bd, le = d2 <= bd;
                fm = lt ? m0 : fm;
                lm = le ? m0 : lm;
                bd = fminf(bd, d2);
            }
            {
                const float d2 = d2v.y;
                const bool lt = d2 < bd, le = d2 <= bd;
                fm = lt ? (m0 + 1) : fm;
                lm = le ? (m0 + 1) : lm;
                bd = fminf(bd, d2);
            }
        }
    }

    red_d[w][lane] = bd;
    red_f[w][lane] = fm;
    red_l[w][lane] = lm;
    __syncthreads();

    if (tid < QG) {
        float b = red_d[0][tid];
        int   f = red_f[0][tid];
        int   l = red_l[0][tid];
        #pragma unroll
        for (int ww = 1; ww < NWAVES; ++ww) {
            const float d = red_d[ww][tid];
            if (d < b)       { b = d; f = red_f[ww][tid]; l = red_l[ww][tid]; }
            else if (d == b) { f = min(f, red_f[ww][tid]);
                               l = max(l, red_l[ww][tid]); }
        }
        // Gap-keyed tie policy (R7/R9): big-gap exact tie -> LAST, else FIRST.
        const int gap = l - f;
        const int idx = (gap >= GAP_LAST_THRESH) ? l : f;
        out[(size_t)batch * NQ + qgroup * QG + tid] = idx + 1;  // base-1
    }
}

extern "C" void kernel_launch(void* const* d_in, const int* in_sizes, int n_in,
                              void* d_out, int out_size, void* d_ws, size_t ws_size,
                              hipStream_t stream) {
    const float* S1 = (const float*)d_in[0];
    const float* S2 = (const float*)d_in[1];
    int* out = (int*)d_out;
    dim3 grid(BATCHES * (NQ / QG));   // 512 blocks = 2 per CU
    dim3 block(512);                  // 8 waves
    sided_distance_kernel<<<grid, block, 0, stream>>>(S1, S2, out);
}

// Round 15
// 122.264 us; speedup vs baseline: 1.1263x; 1.1263x over previous
//
#include <hip/hip_runtime.h>

// SidedDistance: for each point in S1 (B,N,3), index (base-1) of nearest point
// in S2 (B,M,3). B=4, N=M=8192. Output int32. PASSING MODEL (R9/R10/R11/R14,
// absmax=32):
//   d2 bits = fwd-nonFMA expansion:  n = (x*x + y*y) + z*z ;
//   cross = (ax*bx + ay*by) + az*bz ; d2 = fma(cross,-2,n1) + n2
//   (fma form bit-equal to (n1-2c)+n2 since 2c exact; verified R11/R14 pass)
//   tie policy: first & last index of min; emit LAST if gap>=3000 else FIRST;
//   output idx+1.  DO NOT touch numerics/tie policy.
//
// R14 post-mortem: pk packing ADDED instrs (asm operand marshaling; v_pk_f32
// has no throughput gain on CDNA4 - fp32 peak == scalar fma rate) and Pair
// staging caused 524K write bank conflicts. R10's scalar loop is right; its
// 33% idle was grid=256 = exactly 1 block/CU (nothing to overlap barriers).
// R15: R10 scalar inner loop + candidate range split in 2 across blocks
// (grid 512 -> 2 independent 8-wave blocks/CU = 4 waves/SIMD, small barrier
// domains) + partials in d_ws + tiny merge kernel (exact semantics kept).

#define BATCHES 4
#define NQ 8192
#define NM 8192
#define QG 128          // queries per block (2 per lane)
#define NWAVES 8
#define NHALF 2
#define HRANGE (NM / NHALF)      // 4096 candidates per block
#define TILE 2048
#define NTILES (HRANGE / TILE)   // 2
#define NQTOT (BATCHES * NQ)     // 32768
#define GAP_LAST_THRESH 3000

__global__ __launch_bounds__(512, 4)
void sd_partial(const float* __restrict__ S1,
                const float* __restrict__ S2,
                float* __restrict__ wsd, int* __restrict__ wsf,
                int* __restrict__ wsl) {
#pragma clang fp contract(off)
    __shared__ float4 pts[TILE];            // (x, y, z, n2) - 32 KB
    __shared__ float red_d[NWAVES][QG];
    __shared__ int   red_f[NWAVES][QG];
    __shared__ int   red_l[NWAVES][QG];

    const int tid    = threadIdx.x;
    const int lane   = tid & 63;
    const int w      = __builtin_amdgcn_readfirstlane(tid >> 6);
    const int bid    = blockIdx.x;
    const int half   = bid & 1;             // candidate half-range
    const int qgroup = (bid >> 1) & 63;
    const int batch  = bid >> 7;
    const int q0     = qgroup * QG + lane;
    const int q1     = q0 + 64;

    // n1 exactly as np.sum(S1*S1,-1): (x*x + y*y) + z*z, forward, no FMA.
    const float* a0 = S1 + ((size_t)batch * NQ + q0) * 3;
    const float* a1 = S1 + ((size_t)batch * NQ + q1) * 3;
    const float ax0 = a0[0], ay0 = a0[1], az0 = a0[2];
    const float ax1 = a1[0], ay1 = a1[1], az1 = a1[2];
    const float n10 = __fadd_rn(__fadd_rn(__fmul_rn(ax0, ax0), __fmul_rn(ay0, ay0)),
                                __fmul_rn(az0, az0));
    const float n11 = __fadd_rn(__fadd_rn(__fmul_rn(ax1, ax1), __fmul_rn(ay1, ay1)),
                                __fmul_rn(az1, az1));

    float bd0 = 3.4e38f, bd1 = 3.4e38f;
    int   f0 = 0, l0 = 0, f1 = 0, l1 = 0;

    const float* s2b = S2 + (size_t)batch * NM * 3;

    for (int t = 0; t < NTILES; ++t) {
        __syncthreads();   // protect LDS from previous tile's readers
        const float* g = s2b + (size_t)(half * HRANGE + t * TILE) * 3;
        for (int p = tid; p < TILE; p += 512) {
            const float x = g[3 * p], y = g[3 * p + 1], z = g[3 * p + 2];
            const float n2 = __fadd_rn(__fadd_rn(__fmul_rn(x, x), __fmul_rn(y, y)),
                                       __fmul_rn(z, z));
            pts[p] = make_float4(x, y, z, n2);   // 16B stride: conflict-free (R10)
        }
        __syncthreads();

        // Wave w scans local candidates (j<<3)|w: broadcast ds_read_b128.
        const float4* wp = pts + w;
        int m = half * HRANGE + t * TILE + w;    // wave-uniform, +8/iter
        #pragma unroll 16
        for (int j = 0; j < TILE / NWAVES; ++j, m += NWAVES) {
            const float4 p = wp[(size_t)j * NWAVES];
            // --- query 0: bit-exact fwd-nonFMA expansion ---
            const float c0 = __fadd_rn(
                __fadd_rn(__fmul_rn(ax0, p.x), __fmul_rn(ay0, p.y)),
                __fmul_rn(az0, p.z));
            const float d20 = __fadd_rn(__fmaf_rn(c0, -2.0f, n10), p.w);
            const bool lt0 = d20 < bd0, le0 = d20 <= bd0;
            f0  = lt0 ? m : f0;
            l0  = le0 ? m : l0;
            bd0 = fminf(bd0, d20);
            // --- query 1 ---
            const float c1 = __fadd_rn(
                __fadd_rn(__fmul_rn(ax1, p.x), __fmul_rn(ay1, p.y)),
                __fmul_rn(az1, p.z));
            const float d21 = __fadd_rn(__fmaf_rn(c1, -2.0f, n11), p.w);
            const bool lt1 = d21 < bd1, le1 = d21 <= bd1;
            f1  = lt1 ? m : f1;
            l1  = le1 ? m : l1;
            bd1 = fminf(bd1, d21);
        }
    }

    red_d[w][lane]      = bd0;
    red_f[w][lane]      = f0;
    red_l[w][lane]      = l0;
    red_d[w][lane + 64] = bd1;
    red_f[w][lane + 64] = f1;
    red_l[w][lane + 64] = l1;
    __syncthreads();

    if (tid < QG) {
        float bd = red_d[0][tid];
        int   f  = red_f[0][tid];
        int   l  = red_l[0][tid];
        #pragma unroll
        for (int ww = 1; ww < NWAVES; ++ww) {
            const float d = red_d[ww][tid];
            if (d < bd)       { bd = d; f = red_f[ww][tid]; l = red_l[ww][tid]; }
            else if (d == bd) { f = min(f, red_f[ww][tid]);
                                l = max(l, red_l[ww][tid]); }
        }
        // Partial for this candidate half-range.
        const int e = half * NQTOT + batch * NQ + qgroup * QG + tid;
        wsd[e] = bd; wsf[e] = f; wsl[e] = l;
    }
}

__global__ __launch_bounds__(256)
void sd_merge(const float* __restrict__ wsd, const int* __restrict__ wsf,
              const int* __restrict__ wsl, int* __restrict__ out) {
    const int gq = blockIdx.x * 256 + threadIdx.x;   // [0, NQTOT)
    float bd = wsd[gq];
    int   f  = wsf[gq], l = wsl[gq];
    const float b1 = wsd[NQTOT + gq];
    const int   f1 = wsf[NQTOT + gq], l1 = wsl[NQTOT + gq];
    // Ranges ordered (half0 < half1): exact first/last-min merge.
    if (b1 < bd)       { bd = b1; f = f1; l = l1; }
    else if (b1 == bd) { f = min(f, f1); l = max(l, l1); }
    // Gap-keyed tie policy (R7/R9): big-gap exact tie -> LAST, else FIRST.
    const int gap = l - f;
    out[gq] = ((gap >= GAP_LAST_THRESH) ? l : f) + 1;   // base-1
}

extern "C" void kernel_launch(void* const* d_in, const int* in_sizes, int n_in,
                              void* d_out, int out_size, void* d_ws, size_t ws_size,
                              hipStream_t stream) {
    const float* S1 = (const float*)d_in[0];
    const float* S2 = (const float*)d_in[1];
    int* out = (int*)d_out;
    float* wsd = (float*)d_ws;                        // 2*32768 floats
    int*   wsf = (int*)d_ws + 2 * NQTOT;              // 2*32768 ints
    int*   wsl = (int*)d_ws + 4 * NQTOT;              // 2*32768 ints (768 KB total)
    dim3 grid(BATCHES * (NQ / QG) * NHALF);           // 512 blocks = 2 per CU
    dim3 block(512);                                  // 8 waves
    sd_partial<<<grid, block, 0, stream>>>(S1, S2, wsd, wsf, wsl);
    sd_merge<<<NQTOT / 256, 256, 0, stream>>>(wsd, wsf, wsl, out);
}